// Round 1
// baseline (428.414 us; speedup 1.0000x reference)
//
#include <hip/hip_runtime.h>
#include <hip/hip_bf16.h>
#include <math.h>

#define N_NODES 50000
#define N_EDGES 1600000
#define IN_DIM  128
#define OUT_DIM 32
#define N_HEADS 4
#define WH_DIM  (N_HEADS * OUT_DIM)   // 128
#define CAP     128                   // per-node LDS edge cache (max deg ~58)
#define NB_SCAN 196                   // ceil(50000/256)

typedef __attribute__((ext_vector_type(8))) short short8;     // 8 bf16
typedef __attribute__((ext_vector_type(4))) float floatx4;    // MFMA acc

__device__ __forceinline__ short f2bf(float v) {
    __hip_bfloat16 b = __float2bfloat16(v);
    return *reinterpret_cast<short*>(&b);
}
__device__ __forceinline__ float lrelu(float v) {
    return v > 0.0f ? v : 0.2f * v;
}

// ---------------------------------------------------------------------------
// edge_index may arrive as int32 or int64 (reference dtype).
// ---------------------------------------------------------------------------
__device__ __forceinline__ void load_edge(const void* eidx, int is32, int e,
                                          int& s, int& d) {
    if (is32) {
        const int2 v = ((const int2*)eidx)[e];
        s = v.x; d = v.y;
    } else {
        const longlong2 v = ((const longlong2*)eidx)[e];
        s = (int)v.x; d = (int)v.y;
    }
}

// ---------------------------------------------------------------------------
// k_cvt: canonicalize edges to int32 SoA + fused degree histogram.
// dtype self-detect: odd int-words of an int64 buffer are hi-words (all 0,
// ids < 2^31); for int32 they are node ids (nonzero w.h.p.; 64 samples).
// ---------------------------------------------------------------------------
__global__ __launch_bounds__(256) void k_cvt(
        const void* __restrict__ eidx,
        int* __restrict__ s32, int* __restrict__ d32, int* __restrict__ deg) {
    __shared__ int s_is32;
    const int t = threadIdx.x;
    if (t < 64) {
        // max index 2*63*25000+1 = 3150001 < 3.2M ints (int32 buffer size)
        int hi = ((const int*)eidx)[2 * (t * 25000) + 1];
        unsigned long long b = __ballot(hi != 0);
        if (t == 0) s_is32 = (b != 0ULL) ? 1 : 0;
    }
    __syncthreads();
    const int is32 = s_is32;
    const int e = blockIdx.x * 256 + t;
    if (e >= N_EDGES) return;
    int s, d;
    load_edge(eidx, is32, e, s, d);
    s32[e] = s;
    d32[e] = d;
    atomicAdd(&deg[d], 1);
}

// ---------------------------------------------------------------------------
// MFMA GEMM: [64 nodes] x [144 cols] per block, K=128, bf16 inputs.
//   cols   0..127 : Wh  (bf16 out)
//   cols 128..135 : s = x . U where U[k][c] = sum_o W[h][k][o]*a[h][o]
//                   (c<4: a_src head c ; c>=4: a_dst head c-4)  -> f32 out
// ---------------------------------------------------------------------------
__global__ __launch_bounds__(256) void k_wh(
        const float* __restrict__ x, const float* __restrict__ weight,
        const float* __restrict__ attn,
        __hip_bfloat16* __restrict__ Wh16, float* __restrict__ sb16) {
    __shared__ float ubuf[128 * 8];            // 4 KB
    __shared__ short xsw[4 * 4 * 64 * 8];      // 16 KB  [wg][kc][lane][j]
    __shared__ short bsw[4 * 9 * 64 * 8];      // 36 KB  [kc][cg][lane][j]
    const int t  = threadIdx.x;
    const int nb = blockIdx.x * 64;

    // ---- U[k][c], c in [0,8)
    {
        int c = t & 7, k0 = t >> 3;            // k0 in [0,32)
        int h = c & 3;
        const float* ap = attn + h * 64 + (c >> 2) * 32;
        for (int k = k0; k < 128; k += 32) {
            const float* wp = weight + h * (IN_DIM * OUT_DIM) + k * OUT_DIM;
            float u = 0.f;
#pragma unroll
            for (int o = 0; o < 32; o += 4) {
                float4 wv = *(const float4*)(wp + o);
                float4 av = *(const float4*)(ap + o);
                u += wv.x * av.x + wv.y * av.y + wv.z * av.z + wv.w * av.w;
            }
            ubuf[k * 8 + c] = u;
        }
    }
    __syncthreads();

    // ---- stage B: weight cols 0..127
    for (int f = t; f < 128 * 128; f += 256) {
        int k = f >> 7, c = f & 127;
        float w = weight[(c >> 5) * (IN_DIM * OUT_DIM) + k * OUT_DIM + (c & 31)];
        int kc = k >> 5, quad = (k >> 3) & 3, j = k & 7;
        bsw[((kc * 9 + (c >> 4)) * 64 + quad * 16 + (c & 15)) * 8 + j] = f2bf(w);
    }
    // ---- stage B: extension cols 128..143 (U, zero-padded)
    for (int f = t; f < 128 * 16; f += 256) {
        int k = f >> 4, c = f & 15;
        float w = (c < 8) ? ubuf[k * 8 + c] : 0.f;
        int kc = k >> 5, quad = (k >> 3) & 3, j = k & 7;
        bsw[((kc * 9 + 8) * 64 + quad * 16 + c) * 8 + j] = f2bf(w);
    }
    // ---- stage A: 64 node rows of x, f32 -> bf16, swizzled
    for (int f = t; f < 64 * 32; f += 256) {
        int n = f >> 5, k = (f & 31) * 4;
        int ng = nb + n; if (ng > N_NODES - 1) ng = N_NODES - 1;
        float4 v = *(const float4*)(x + (size_t)ng * IN_DIM + k);
        int wg = n >> 4, m = n & 15, kc = k >> 5, quad = (k >> 3) & 3, j = k & 7;
        short4 sv = make_short4(f2bf(v.x), f2bf(v.y), f2bf(v.z), f2bf(v.w));
        *(short4*)&xsw[(((wg * 4 + kc) * 64) + quad * 16 + m) * 8 + j] = sv;
    }
    __syncthreads();

    // ---- compute: per wave, 16 nodes x 144 cols, 36 MFMAs
    const int wg = t >> 6, lane = t & 63;
    floatx4 acc[9];
#pragma unroll
    for (int i = 0; i < 9; ++i) acc[i] = (floatx4){0.f, 0.f, 0.f, 0.f};
#pragma unroll
    for (int kc = 0; kc < 4; ++kc) {
        short8 a = *(short8*)&xsw[((wg * 4 + kc) * 64 + lane) * 8];
#pragma unroll
        for (int cg = 0; cg < 9; ++cg) {
            short8 b = *(short8*)&bsw[((kc * 9 + cg) * 64 + lane) * 8];
            acc[cg] = __builtin_amdgcn_mfma_f32_16x16x32_bf16(a, b, acc[cg],
                                                              0, 0, 0);
        }
    }

    // ---- epilogue
    const int col = lane & 15, quad = lane >> 4;
#pragma unroll
    for (int r = 0; r < 4; ++r) {
        int n = nb + wg * 16 + quad * 4 + r;
        if (n >= N_NODES) continue;
#pragma unroll
        for (int cg = 0; cg < 8; ++cg)
            Wh16[(size_t)n * WH_DIM + cg * 16 + col] =
                __float2bfloat16(acc[cg][r]);
        if (col < 8) sb16[(size_t)n * 16 + col] = acc[8][r];
    }
}

// ---------------------------------------------------------------------------
// scan: per-dst degree -> exclusive offsets (pre + bbase hierarchy)
// ---------------------------------------------------------------------------
__global__ __launch_bounds__(256) void k_scan1(
        const int* __restrict__ deg, int* __restrict__ pre,
        int* __restrict__ bsum) {
    __shared__ int sh[256];
    const int t = threadIdx.x;
    const int i = blockIdx.x * 256 + t;
    int v = (i < N_NODES) ? deg[i] : 0;
    sh[t] = v;
    __syncthreads();
    for (int d = 1; d < 256; d <<= 1) {
        int u = (t >= d) ? sh[t - d] : 0;
        __syncthreads();
        sh[t] += u;
        __syncthreads();
    }
    if (i < N_NODES) pre[i] = sh[t] - v;
    if (t == 255) bsum[blockIdx.x] = sh[255];
}

// k_scan2off: every block redundantly scans the 196 block sums, then emits
// bbase[b] and the ready-to-atomically-bump start offsets off[i].
__global__ __launch_bounds__(256) void k_scan2off(
        const int* __restrict__ bsum, int* __restrict__ bbase,
        const int* __restrict__ pre, int* __restrict__ off) {
    __shared__ int sh[256];
    const int t = threadIdx.x;
    int v = (t < NB_SCAN) ? bsum[t] : 0;
    sh[t] = v;
    __syncthreads();
    for (int d = 1; d < 256; d <<= 1) {
        int u = (t >= d) ? sh[t - d] : 0;
        __syncthreads();
        sh[t] += u;
        __syncthreads();
    }
    const int b = blockIdx.x;
    const int exb = sh[b] - bsum[b];           // exclusive prefix for block b
    if (t == 0) bbase[b] = exb;
    const int i = b * 256 + t;
    if (i < N_NODES) off[i] = pre[i] + exb;
}

// ---------------------------------------------------------------------------
// k_scatter2: single pass, position via global atomic on off[d].
// Order within a dst segment is nondeterministic (fp-reorder noise only).
// ---------------------------------------------------------------------------
__global__ __launch_bounds__(256) void k_scatter2(
        const int* __restrict__ s32, const int* __restrict__ d32,
        int* __restrict__ off, int* __restrict__ csr) {
    const int e = blockIdx.x * 256 + threadIdx.x;
    if (e >= N_EDGES) return;
    const int p = atomicAdd(&off[d32[e]], 1);
    csr[p] = s32[e];
}

// ---------------------------------------------------------------------------
// One wave per dst node. No max pass (softmax shift-invariant; |e| small).
// sb16 row: [0..3]=s_src, [4..7]=s_dst, [8..11]=inv (written here), 64 B.
// Phase D lane map: esl = t>>4 picks 1 of 4 edges, dsl = t&15 picks an
// 8-dim slice -> one dwordx4 covers 4 edges per wave-instruction (was 1).
// inv applied once after the cross-esl shuffle reduce (sum is inv-linear).
// ---------------------------------------------------------------------------
__global__ __launch_bounds__(256) void k_node(
        const int* __restrict__ pre, const int* __restrict__ bbase,
        const int* __restrict__ csr, float* __restrict__ sb16,
        const __hip_bfloat16* __restrict__ Wh16,
        float* __restrict__ out_h) {
    __shared__ int    sbuf[4][CAP];
    __shared__ float4 e4b[4][CAP];                      // exp(e) values
    const int wv = threadIdx.x >> 6;
    const int t  = threadIdx.x & 63;
    const int n  = blockIdx.x * 4 + wv;
    const int beg = pre[n] + bbase[n >> 8];
    const int end = (n + 1 < N_NODES) ? pre[n + 1] + bbase[(n + 1) >> 8]
                                      : N_EDGES;
    const int deg = end - beg;

    const float4 sd = *(const float4*)(sb16 + (size_t)n * 16 + 4);

    // Phase A: ex = exp(lrelu(s_src[src] + s_dst[n])); cache; running sum
    float4 sum = {0.f, 0.f, 0.f, 0.f};
    for (int l = t; l < deg; l += 64) {
        int s = csr[beg + l];
        float4 ss = *(const float4*)(sb16 + (size_t)s * 16);
        float4 ex;
        ex.x = __expf(lrelu(ss.x + sd.x));
        ex.y = __expf(lrelu(ss.y + sd.y));
        ex.z = __expf(lrelu(ss.z + sd.z));
        ex.w = __expf(lrelu(ss.w + sd.w));
        if (l < CAP) { sbuf[wv][l] = s; e4b[wv][l] = ex; }
        sum.x += ex.x; sum.y += ex.y; sum.z += ex.z; sum.w += ex.w;
    }
#pragma unroll
    for (int o = 32; o; o >>= 1) {
        sum.x += __shfl_xor(sum.x, o);
        sum.y += __shfl_xor(sum.y, o);
        sum.z += __shfl_xor(sum.z, o);
        sum.w += __shfl_xor(sum.w, o);
    }
    float4 inv;
    inv.x = 1.0f / (sum.x + 1e-9f); inv.y = 1.0f / (sum.y + 1e-9f);
    inv.z = 1.0f / (sum.z + 1e-9f); inv.w = 1.0f / (sum.w + 1e-9f);
    if (t == 0) *(float4*)(sb16 + (size_t)n * 16 + 8) = inv;

    // Phase D: out[n, dsl*8 .. dsl*8+7] = inv[h] * sum_j ex_j[h]*Wh16[s_j]
    const int esl = t >> 4;            // edge slot within 4-edge group
    const int dsl = t & 15;            // 8-dim slice: dims [dsl*8, dsl*8+8)
    const int h   = dsl >> 2;          // head of this slice (8 | 32)
    const float invh = (h == 0) ? inv.x : (h == 1) ? inv.y
                     : (h == 2) ? inv.z : inv.w;
    const float sdh  = (h == 0) ? sd.x : (h == 1) ? sd.y
                     : (h == 2) ? sd.z : sd.w;
    float acc0 = 0.f, acc1 = 0.f, acc2 = 0.f, acc3 = 0.f;
    float acc4 = 0.f, acc5 = 0.f, acc6 = 0.f, acc7 = 0.f;
    for (int jb = 0; jb < deg; jb += 4) {
        const int idx = jb + esl;
        float a = 0.f;
        int s = sbuf[wv][0];           // safe pad row (deg>0 inside loop)
        if (idx < deg) {
            if (idx < CAP) {
                s = sbuf[wv][idx];
                a = ((const float*)&e4b[wv][idx])[h];
            } else {                   // unreachable for this graph (deg<=~58)
                s = csr[beg + idx];
                a = __expf(lrelu(sb16[(size_t)s * 16 + h] + sdh));
            }
        }
        const uint4 w = *(const uint4*)(Wh16 + (size_t)s * WH_DIM + dsl * 8);
        float f0 = __uint_as_float(w.x << 16);
        float f1 = __uint_as_float(w.x & 0xffff0000u);
        float f2 = __uint_as_float(w.y << 16);
        float f3 = __uint_as_float(w.y & 0xffff0000u);
        float f4 = __uint_as_float(w.z << 16);
        float f5 = __uint_as_float(w.z & 0xffff0000u);
        float f6 = __uint_as_float(w.w << 16);
        float f7 = __uint_as_float(w.w & 0xffff0000u);
        acc0 += a * f0; acc1 += a * f1; acc2 += a * f2; acc3 += a * f3;
        acc4 += a * f4; acc5 += a * f5; acc6 += a * f6; acc7 += a * f7;
    }
    // reduce across the 4 edge slots (lanes dsl, dsl+16, dsl+32, dsl+48)
    acc0 += __shfl_xor(acc0, 16); acc0 += __shfl_xor(acc0, 32);
    acc1 += __shfl_xor(acc1, 16); acc1 += __shfl_xor(acc1, 32);
    acc2 += __shfl_xor(acc2, 16); acc2 += __shfl_xor(acc2, 32);
    acc3 += __shfl_xor(acc3, 16); acc3 += __shfl_xor(acc3, 32);
    acc4 += __shfl_xor(acc4, 16); acc4 += __shfl_xor(acc4, 32);
    acc5 += __shfl_xor(acc5, 16); acc5 += __shfl_xor(acc5, 32);
    acc6 += __shfl_xor(acc6, 16); acc6 += __shfl_xor(acc6, 32);
    acc7 += __shfl_xor(acc7, 16); acc7 += __shfl_xor(acc7, 32);
    if (t < 16) {
        float* op = out_h + (size_t)n * WH_DIM + dsl * 8;
        float4 o0 = {acc0 * invh, acc1 * invh, acc2 * invh, acc3 * invh};
        float4 o1 = {acc4 * invh, acc5 * invh, acc6 * invh, acc7 * invh};
        *(float4*)op = o0;
        *(float4*)(op + 4) = o1;
    }
}

// ---------------------------------------------------------------------------
// Edge-parallel alpha: coalesced edge reads; dst-side gather (sd+inv) hits
// one 64 B line per edge; coalesced float4 write.
// ---------------------------------------------------------------------------
__global__ __launch_bounds__(256) void k_alpha(
        const int* __restrict__ s32, const int* __restrict__ d32,
        const float* __restrict__ sb16, float* __restrict__ ebuf) {
    int e = blockIdx.x * 256 + threadIdx.x;
    if (e >= N_EDGES) return;
    int s = s32[e], d = d32[e];
    float4 ss = *(const float4*)(sb16 + (size_t)s * 16);
    float4 sd = *(const float4*)(sb16 + (size_t)d * 16 + 4);
    float4 iv = *(const float4*)(sb16 + (size_t)d * 16 + 8);
    float4 a;
    a.x = __expf(lrelu(ss.x + sd.x)) * iv.x;
    a.y = __expf(lrelu(ss.y + sd.y)) * iv.y;
    a.z = __expf(lrelu(ss.z + sd.z)) * iv.z;
    a.w = __expf(lrelu(ss.w + sd.w)) * iv.w;
    *(float4*)(ebuf + (size_t)e * 4) = a;
}

// ---------------------------------------------------------------------------
extern "C" void kernel_launch(void* const* d_in, const int* in_sizes, int n_in,
                              void* d_out, int out_size, void* d_ws, size_t ws_size,
                              hipStream_t stream) {
    const float* x      = (const float*)d_in[0];
    const void*  eidx   = d_in[1];
    const float* weight = (const float*)d_in[2];
    const float* attn   = (const float*)d_in[3];

    float* out   = (float*)d_out;
    float* out_h = out;                                   // [N_NODES, 128]
    float* ebuf  = out + (size_t)N_NODES * WH_DIM;        // [N_EDGES, 4] alpha

    // workspace layout (64-B aligned); total ~36.0 MB
    char* ws = (char*)d_ws;
    int*   bsum  = (int*)ws;                              // 784 B
    int*   bbase = (int*)(ws + 1024);                     // 784 B
    int*   deg   = (int*)(ws + 2048);                     // 200000 B
    int*   pre   = (int*)(ws + 202112);                   // 200000 B
    int*   off   = (int*)(ws + 402176);                   // 200000 B
    int*   s32   = (int*)(ws + 602176);                   // 6.4 MB
    int*   d32   = (int*)(ws + 7002176);                  // 6.4 MB
    int*   csr   = (int*)(ws + 13402176);                 // 6.4 MB
    __hip_bfloat16* Wh16 = (__hip_bfloat16*)(ws + 19802176);  // 12.8 MB
    float* sb16  = (float*)(ws + 32602176);               // 3.2 MB [n][16]

    hipMemsetAsync(deg, 0, N_NODES * sizeof(int), stream);

    k_cvt<<<(N_EDGES + 255) / 256, 256, 0, stream>>>(eidx, s32, d32, deg);
    k_wh<<<(N_NODES + 63) / 64, 256, 0, stream>>>(x, weight, attn, Wh16, sb16);
    k_scan1<<<NB_SCAN, 256, 0, stream>>>(deg, pre, bsum);
    k_scan2off<<<NB_SCAN, 256, 0, stream>>>(bsum, bbase, pre, off);
    k_scatter2<<<(N_EDGES + 255) / 256, 256, 0, stream>>>(s32, d32, off, csr);
    k_node<<<N_NODES / 4, 256, 0, stream>>>(pre, bbase, csr, sb16,
                                            Wh16, out_h);
    k_alpha<<<(N_EDGES + 255) / 256, 256, 0, stream>>>(s32, d32, sb16, ebuf);
}

// Round 2
// 280.793 us; speedup vs baseline: 1.5257x; 1.5257x over previous
//
#include <hip/hip_runtime.h>
#include <hip/hip_bf16.h>
#include <math.h>

#define N_NODES 50000
#define N_EDGES 1600000
#define IN_DIM  128
#define OUT_DIM 32
#define N_HEADS 4
#define WH_DIM  (N_HEADS * OUT_DIM)   // 128
#define CAP     128                   // per-node LDS edge cache (max deg ~58)
#define NB_SCAN 196                   // ceil(50000/256)
#define NPASS   4                     // dst-windows
#define WIN     (N_NODES / NPASS)     // 12500
#define NCHUNK  32                    // edge chunks for counting sort
#define CE      (N_EDGES / NCHUNK)    // 50000 edges per chunk

typedef __attribute__((ext_vector_type(8))) short short8;     // 8 bf16
typedef __attribute__((ext_vector_type(4))) float floatx4;    // MFMA acc

__device__ __forceinline__ short f2bf(float v) {
    __hip_bfloat16 b = __float2bfloat16(v);
    return *reinterpret_cast<short*>(&b);
}
__device__ __forceinline__ float lrelu(float v) {
    return v > 0.0f ? v : 0.2f * v;
}

// ---------------------------------------------------------------------------
// edge_index may arrive as int32 or int64 (reference dtype).
// ---------------------------------------------------------------------------
__device__ __forceinline__ void load_edge(const void* eidx, int is32, int e,
                                          int& s, int& d) {
    if (is32) {
        const int2 v = ((const int2*)eidx)[e];
        s = v.x; d = v.y;
    } else {
        const longlong2 v = ((const longlong2*)eidx)[e];
        s = (int)v.x; d = (int)v.y;
    }
}

// ---------------------------------------------------------------------------
// k_cvt: canonicalize edges to int32 SoA (coalesced, no atomics).
// dtype self-detect per block: odd int-words of an int64 buffer are hi-words
// (all 0, ids < 2^31); for int32 they are node ids (nonzero w.h.p.; 64
// samples -> P(miss) ~ (1/50000)^64).
// ---------------------------------------------------------------------------
__global__ __launch_bounds__(256) void k_cvt(
        const void* __restrict__ eidx,
        int* __restrict__ s32, int* __restrict__ d32) {
    __shared__ int s_is32;
    const int t = threadIdx.x;
    if (t < 64) {
        // max index 2*63*25000+1 = 3150001 < 3.2M ints (int32 buffer size)
        int hi = ((const int*)eidx)[2 * (t * 25000) + 1];
        unsigned long long b = __ballot(hi != 0);
        if (t == 0) s_is32 = (b != 0ULL) ? 1 : 0;
    }
    __syncthreads();
    const int is32 = s_is32;
    const int e = blockIdx.x * 256 + t;
    if (e >= N_EDGES) return;
    int s, d;
    load_edge(eidx, is32, e, s, d);
    s32[e] = s;
    d32[e] = d;
}

// ---------------------------------------------------------------------------
// MFMA GEMM: [64 nodes] x [144 cols] per block, K=128, bf16 inputs.
//   cols   0..127 : Wh  (bf16 out)
//   cols 128..135 : s = x . U where U[k][c] = sum_o W[h][k][o]*a[h][o]
//                   (c<4: a_src head c ; c>=4: a_dst head c-4)  -> f32 out
// ---------------------------------------------------------------------------
__global__ __launch_bounds__(256) void k_wh(
        const float* __restrict__ x, const float* __restrict__ weight,
        const float* __restrict__ attn,
        __hip_bfloat16* __restrict__ Wh16, float* __restrict__ sb16) {
    __shared__ float ubuf[128 * 8];            // 4 KB
    __shared__ short xsw[4 * 4 * 64 * 8];      // 16 KB  [wg][kc][lane][j]
    __shared__ short bsw[4 * 9 * 64 * 8];      // 36 KB  [kc][cg][lane][j]
    const int t  = threadIdx.x;
    const int nb = blockIdx.x * 64;

    // ---- U[k][c], c in [0,8)
    {
        int c = t & 7, k0 = t >> 3;            // k0 in [0,32)
        int h = c & 3;
        const float* ap = attn + h * 64 + (c >> 2) * 32;
        for (int k = k0; k < 128; k += 32) {
            const float* wp = weight + h * (IN_DIM * OUT_DIM) + k * OUT_DIM;
            float u = 0.f;
#pragma unroll
            for (int o = 0; o < 32; o += 4) {
                float4 wv = *(const float4*)(wp + o);
                float4 av = *(const float4*)(ap + o);
                u += wv.x * av.x + wv.y * av.y + wv.z * av.z + wv.w * av.w;
            }
            ubuf[k * 8 + c] = u;
        }
    }
    __syncthreads();

    // ---- stage B: weight cols 0..127
    for (int f = t; f < 128 * 128; f += 256) {
        int k = f >> 7, c = f & 127;
        float w = weight[(c >> 5) * (IN_DIM * OUT_DIM) + k * OUT_DIM + (c & 31)];
        int kc = k >> 5, quad = (k >> 3) & 3, j = k & 7;
        bsw[((kc * 9 + (c >> 4)) * 64 + quad * 16 + (c & 15)) * 8 + j] = f2bf(w);
    }
    // ---- stage B: extension cols 128..143 (U, zero-padded)
    for (int f = t; f < 128 * 16; f += 256) {
        int k = f >> 4, c = f & 15;
        float w = (c < 8) ? ubuf[k * 8 + c] : 0.f;
        int kc = k >> 5, quad = (k >> 3) & 3, j = k & 7;
        bsw[((kc * 9 + 8) * 64 + quad * 16 + c) * 8 + j] = f2bf(w);
    }
    // ---- stage A: 64 node rows of x, f32 -> bf16, swizzled
    for (int f = t; f < 64 * 32; f += 256) {
        int n = f >> 5, k = (f & 31) * 4;
        int ng = nb + n; if (ng > N_NODES - 1) ng = N_NODES - 1;
        float4 v = *(const float4*)(x + (size_t)ng * IN_DIM + k);
        int wg = n >> 4, m = n & 15, kc = k >> 5, quad = (k >> 3) & 3, j = k & 7;
        short4 sv = make_short4(f2bf(v.x), f2bf(v.y), f2bf(v.z), f2bf(v.w));
        *(short4*)&xsw[(((wg * 4 + kc) * 64) + quad * 16 + m) * 8 + j] = sv;
    }
    __syncthreads();

    // ---- compute: per wave, 16 nodes x 144 cols, 36 MFMAs
    const int wg = t >> 6, lane = t & 63;
    floatx4 acc[9];
#pragma unroll
    for (int i = 0; i < 9; ++i) acc[i] = (floatx4){0.f, 0.f, 0.f, 0.f};
#pragma unroll
    for (int kc = 0; kc < 4; ++kc) {
        short8 a = *(short8*)&xsw[((wg * 4 + kc) * 64 + lane) * 8];
#pragma unroll
        for (int cg = 0; cg < 9; ++cg) {
            short8 b = *(short8*)&bsw[((kc * 9 + cg) * 64 + lane) * 8];
            acc[cg] = __builtin_amdgcn_mfma_f32_16x16x32_bf16(a, b, acc[cg],
                                                              0, 0, 0);
        }
    }

    // ---- epilogue
    const int col = lane & 15, quad = lane >> 4;
#pragma unroll
    for (int r = 0; r < 4; ++r) {
        int n = nb + wg * 16 + quad * 4 + r;
        if (n >= N_NODES) continue;
#pragma unroll
        for (int cg = 0; cg < 8; ++cg)
            Wh16[(size_t)n * WH_DIM + cg * 16 + col] =
                __float2bfloat16(acc[cg][r]);
        if (col < 8) sb16[(size_t)n * 16 + col] = acc[8][r];
    }
}

// ---------------------------------------------------------------------------
// k_hist: (chunk, window) blocks; LDS histogram, coalesced flush, no atomics.
// ---------------------------------------------------------------------------
__global__ __launch_bounds__(1024) void k_hist(
        const int* __restrict__ d32, int* __restrict__ hist) {
    __shared__ int hbin[WIN];                  // 50 KB
    const int c = blockIdx.x, w = blockIdx.y;
    for (int i = threadIdx.x; i < WIN; i += 1024) hbin[i] = 0;
    __syncthreads();
    const int w0 = w * WIN;
    for (int e = c * CE + threadIdx.x; e < (c + 1) * CE; e += 1024) {
        unsigned u = (unsigned)(d32[e] - w0);
        if (u < WIN) atomicAdd(&hbin[u], 1);
    }
    __syncthreads();
    for (int i = threadIdx.x; i < WIN; i += 1024)
        hist[c * N_NODES + w0 + i] = hbin[i];
}

// ---------------------------------------------------------------------------
// scan: per-dst total over chunks + hierarchical exclusive scan
// off[n] = pre[n] + bbase[n>>8]
// ---------------------------------------------------------------------------
__global__ __launch_bounds__(256) void k_scan1(
        const int* __restrict__ hist, int* __restrict__ pre,
        int* __restrict__ bsum) {
    __shared__ int sh[256];
    const int t = threadIdx.x;
    const int i = blockIdx.x * 256 + t;
    int v = 0;
    if (i < N_NODES)
        for (int c = 0; c < NCHUNK; ++c) v += hist[c * N_NODES + i];
    sh[t] = v;
    __syncthreads();
    for (int d = 1; d < 256; d <<= 1) {
        int u = (t >= d) ? sh[t - d] : 0;
        __syncthreads();
        sh[t] += u;
        __syncthreads();
    }
    if (i < N_NODES) pre[i] = sh[t] - v;
    if (t == 255) bsum[blockIdx.x] = sh[255];
}

__global__ __launch_bounds__(256) void k_scan2(
        const int* __restrict__ bsum, int* __restrict__ bbase) {
    __shared__ int sh[256];
    const int t = threadIdx.x;
    int v = (t < NB_SCAN) ? bsum[t] : 0;
    sh[t] = v;
    __syncthreads();
    for (int d = 1; d < 256; d <<= 1) {
        int u = (t >= d) ? sh[t - d] : 0;
        __syncthreads();
        sh[t] += u;
        __syncthreads();
    }
    if (t < NB_SCAN) bbase[t] = sh[t] - v;
}

// ---------------------------------------------------------------------------
// k_base: in place, hist[c][d] := off[d] + sum_{c'<c} hist[c'][d]
// ---------------------------------------------------------------------------
__global__ __launch_bounds__(256) void k_base(
        const int* __restrict__ pre, const int* __restrict__ bbase,
        int* __restrict__ hist) {
    int d = blockIdx.x * 256 + threadIdx.x;
    if (d >= N_NODES) return;
    int run = pre[d] + bbase[d >> 8];
    for (int c = 0; c < NCHUNK; ++c) {
        int t0 = hist[c * N_NODES + d];
        hist[c * N_NODES + d] = run;
        run += t0;
    }
}

// ---------------------------------------------------------------------------
// k_scatter: (chunk, window) blocks; positions via LDS atomics on bases.
// Window csr region ~1.6 MB stays L2-resident (R4-proven pattern).
// ---------------------------------------------------------------------------
__global__ __launch_bounds__(1024) void k_scatter(
        const int* __restrict__ s32, const int* __restrict__ d32,
        const int* __restrict__ hist, int* __restrict__ csr) {
    __shared__ int pos[WIN];                   // 50 KB
    const int c = blockIdx.x, w = blockIdx.y;
    const int w0 = w * WIN;
    for (int i = threadIdx.x; i < WIN; i += 1024)
        pos[i] = hist[c * N_NODES + w0 + i];
    __syncthreads();
    for (int e = c * CE + threadIdx.x; e < (c + 1) * CE; e += 1024) {
        unsigned u = (unsigned)(d32[e] - w0);
        if (u < WIN) {
            int p = atomicAdd(&pos[u], 1);
            csr[p] = s32[e];
        }
    }
}

// ---------------------------------------------------------------------------
// One wave per dst node. No max pass (softmax shift-invariant; |e| small).
// sb16 row: [0..3]=s_src, [4..7]=s_dst, [8..11]=inv (written here), 64 B.
// Phase D lane map: esl = t>>4 picks 1 of 4 edges, dsl = t&15 picks an
// 8-dim slice -> one dwordx4 covers 4 edges per wave-instruction (was 1).
// inv applied once after the cross-esl shuffle reduce (sum is inv-linear).
// ---------------------------------------------------------------------------
__global__ __launch_bounds__(256) void k_node(
        const int* __restrict__ pre, const int* __restrict__ bbase,
        const int* __restrict__ csr, float* __restrict__ sb16,
        const __hip_bfloat16* __restrict__ Wh16,
        float* __restrict__ out_h) {
    __shared__ int    sbuf[4][CAP];
    __shared__ float4 e4b[4][CAP];                      // exp(e) values
    const int wv = threadIdx.x >> 6;
    const int t  = threadIdx.x & 63;
    const int n  = blockIdx.x * 4 + wv;
    const int beg = pre[n] + bbase[n >> 8];
    const int end = (n + 1 < N_NODES) ? pre[n + 1] + bbase[(n + 1) >> 8]
                                      : N_EDGES;
    const int deg = end - beg;

    const float4 sd = *(const float4*)(sb16 + (size_t)n * 16 + 4);

    // Phase A: ex = exp(lrelu(s_src[src] + s_dst[n])); cache; running sum
    float4 sum = {0.f, 0.f, 0.f, 0.f};
    for (int l = t; l < deg; l += 64) {
        int s = csr[beg + l];
        float4 ss = *(const float4*)(sb16 + (size_t)s * 16);
        float4 ex;
        ex.x = __expf(lrelu(ss.x + sd.x));
        ex.y = __expf(lrelu(ss.y + sd.y));
        ex.z = __expf(lrelu(ss.z + sd.z));
        ex.w = __expf(lrelu(ss.w + sd.w));
        if (l < CAP) { sbuf[wv][l] = s; e4b[wv][l] = ex; }
        sum.x += ex.x; sum.y += ex.y; sum.z += ex.z; sum.w += ex.w;
    }
#pragma unroll
    for (int o = 32; o; o >>= 1) {
        sum.x += __shfl_xor(sum.x, o);
        sum.y += __shfl_xor(sum.y, o);
        sum.z += __shfl_xor(sum.z, o);
        sum.w += __shfl_xor(sum.w, o);
    }
    float4 inv;
    inv.x = 1.0f / (sum.x + 1e-9f); inv.y = 1.0f / (sum.y + 1e-9f);
    inv.z = 1.0f / (sum.z + 1e-9f); inv.w = 1.0f / (sum.w + 1e-9f);
    if (t == 0) *(float4*)(sb16 + (size_t)n * 16 + 8) = inv;

    // Phase D: out[n, dsl*8 .. dsl*8+7] = inv[h] * sum_j ex_j[h]*Wh16[s_j]
    const int esl = t >> 4;            // edge slot within 4-edge group
    const int dsl = t & 15;            // 8-dim slice: dims [dsl*8, dsl*8+8)
    const int h   = dsl >> 2;          // head of this slice (8 | 32)
    const float invh = (h == 0) ? inv.x : (h == 1) ? inv.y
                     : (h == 2) ? inv.z : inv.w;
    const float sdh  = (h == 0) ? sd.x : (h == 1) ? sd.y
                     : (h == 2) ? sd.z : sd.w;
    float acc0 = 0.f, acc1 = 0.f, acc2 = 0.f, acc3 = 0.f;
    float acc4 = 0.f, acc5 = 0.f, acc6 = 0.f, acc7 = 0.f;
    for (int jb = 0; jb < deg; jb += 4) {
        const int idx = jb + esl;
        float a = 0.f;
        int s = sbuf[wv][0];           // safe pad row (deg>0 inside loop)
        if (idx < deg) {
            if (idx < CAP) {
                s = sbuf[wv][idx];
                a = ((const float*)&e4b[wv][idx])[h];
            } else {                   // unreachable for this graph (deg<=~58)
                s = csr[beg + idx];
                a = __expf(lrelu(sb16[(size_t)s * 16 + h] + sdh));
            }
        }
        const uint4 w = *(const uint4*)(Wh16 + (size_t)s * WH_DIM + dsl * 8);
        float f0 = __uint_as_float(w.x << 16);
        float f1 = __uint_as_float(w.x & 0xffff0000u);
        float f2 = __uint_as_float(w.y << 16);
        float f3 = __uint_as_float(w.y & 0xffff0000u);
        float f4 = __uint_as_float(w.z << 16);
        float f5 = __uint_as_float(w.z & 0xffff0000u);
        float f6 = __uint_as_float(w.w << 16);
        float f7 = __uint_as_float(w.w & 0xffff0000u);
        acc0 += a * f0; acc1 += a * f1; acc2 += a * f2; acc3 += a * f3;
        acc4 += a * f4; acc5 += a * f5; acc6 += a * f6; acc7 += a * f7;
    }
    // reduce across the 4 edge slots (lanes dsl, dsl+16, dsl+32, dsl+48)
    acc0 += __shfl_xor(acc0, 16); acc0 += __shfl_xor(acc0, 32);
    acc1 += __shfl_xor(acc1, 16); acc1 += __shfl_xor(acc1, 32);
    acc2 += __shfl_xor(acc2, 16); acc2 += __shfl_xor(acc2, 32);
    acc3 += __shfl_xor(acc3, 16); acc3 += __shfl_xor(acc3, 32);
    acc4 += __shfl_xor(acc4, 16); acc4 += __shfl_xor(acc4, 32);
    acc5 += __shfl_xor(acc5, 16); acc5 += __shfl_xor(acc5, 32);
    acc6 += __shfl_xor(acc6, 16); acc6 += __shfl_xor(acc6, 32);
    acc7 += __shfl_xor(acc7, 16); acc7 += __shfl_xor(acc7, 32);
    if (t < 16) {
        float* op = out_h + (size_t)n * WH_DIM + dsl * 8;
        float4 o0 = {acc0 * invh, acc1 * invh, acc2 * invh, acc3 * invh};
        float4 o1 = {acc4 * invh, acc5 * invh, acc6 * invh, acc7 * invh};
        *(float4*)op = o0;
        *(float4*)(op + 4) = o1;
    }
}

// ---------------------------------------------------------------------------
// Edge-parallel alpha: coalesced edge reads; dst-side gather (sd+inv) hits
// one 64 B line per edge; coalesced float4 write.
// ---------------------------------------------------------------------------
__global__ __launch_bounds__(256) void k_alpha(
        const int* __restrict__ s32, const int* __restrict__ d32,
        const float* __restrict__ sb16, float* __restrict__ ebuf) {
    int e = blockIdx.x * 256 + threadIdx.x;
    if (e >= N_EDGES) return;
    int s = s32[e], d = d32[e];
    float4 ss = *(const float4*)(sb16 + (size_t)s * 16);
    float4 sd = *(const float4*)(sb16 + (size_t)d * 16 + 4);
    float4 iv = *(const float4*)(sb16 + (size_t)d * 16 + 8);
    float4 a;
    a.x = __expf(lrelu(ss.x + sd.x)) * iv.x;
    a.y = __expf(lrelu(ss.y + sd.y)) * iv.y;
    a.z = __expf(lrelu(ss.z + sd.z)) * iv.z;
    a.w = __expf(lrelu(ss.w + sd.w)) * iv.w;
    *(float4*)(ebuf + (size_t)e * 4) = a;
}

// ---------------------------------------------------------------------------
extern "C" void kernel_launch(void* const* d_in, const int* in_sizes, int n_in,
                              void* d_out, int out_size, void* d_ws, size_t ws_size,
                              hipStream_t stream) {
    const float* x      = (const float*)d_in[0];
    const void*  eidx   = d_in[1];
    const float* weight = (const float*)d_in[2];
    const float* attn   = (const float*)d_in[3];

    float* out   = (float*)d_out;
    float* out_h = out;                                   // [N_NODES, 128]
    float* ebuf  = out + (size_t)N_NODES * WH_DIM;        // [N_EDGES, 4] alpha

    // workspace layout (64-B aligned); total ~41.8 MB (R0-proven)
    char* ws = (char*)d_ws;
    int*   bsum  = (int*)(ws + 64);                       // 784 B
    int*   bbase = (int*)(ws + 896);                      // 784 B
    int*   pre   = (int*)(ws + 2048);                     // 200000 B
    int*   s32   = (int*)(ws + 202112);                   // 6.4 MB
    int*   d32   = (int*)(ws + 6602112);                  // 6.4 MB
    int*   hist  = (int*)(ws + 13002112);                 // 6.4 MB [c][d]
    int*   csr   = (int*)(ws + 19402112);                 // 6.4 MB
    __hip_bfloat16* Wh16 = (__hip_bfloat16*)(ws + 25802112);  // 12.8 MB
    float* sb16  = (float*)(ws + 38602112);               // 3.2 MB [n][16]

    k_cvt<<<(N_EDGES + 255) / 256, 256, 0, stream>>>(eidx, s32, d32);
    k_wh<<<(N_NODES + 63) / 64, 256, 0, stream>>>(x, weight, attn, Wh16, sb16);
    dim3 hg(NCHUNK, NPASS);
    k_hist<<<hg, 1024, 0, stream>>>(d32, hist);
    k_scan1<<<NB_SCAN, 256, 0, stream>>>(hist, pre, bsum);
    k_scan2<<<1, 256, 0, stream>>>(bsum, bbase);
    k_base<<<NB_SCAN, 256, 0, stream>>>(pre, bbase, hist);
    k_scatter<<<hg, 1024, 0, stream>>>(s32, d32, hist, csr);
    k_node<<<N_NODES / 4, 256, 0, stream>>>(pre, bbase, csr, sb16,
                                            Wh16, out_h);
    k_alpha<<<(N_EDGES + 255) / 256, 256, 0, stream>>>(s32, d32, sb16, ebuf);
}

// Round 3
// 276.693 us; speedup vs baseline: 1.5483x; 1.0148x over previous
//
#include <hip/hip_runtime.h>
#include <hip/hip_bf16.h>
#include <math.h>

#define N_NODES 50000
#define N_EDGES 1600000
#define IN_DIM  128
#define OUT_DIM 32
#define N_HEADS 4
#define WH_DIM  (N_HEADS * OUT_DIM)   // 128
#define CAP     128                   // per-node LDS edge cache (max deg ~58)
#define NB_SCAN 196                   // ceil(50000/256)
#define NPASS   4                     // dst-windows
#define WIN     (N_NODES / NPASS)     // 12500
#define NCHUNK  32                    // edge chunks for counting sort
#define CE      (N_EDGES / NCHUNK)    // 50000 edges per chunk

typedef __attribute__((ext_vector_type(8))) short short8;     // 8 bf16
typedef __attribute__((ext_vector_type(4))) float floatx4;    // MFMA acc

__device__ __forceinline__ short f2bf(float v) {
    __hip_bfloat16 b = __float2bfloat16(v);
    return *reinterpret_cast<short*>(&b);
}
__device__ __forceinline__ float lrelu(float v) {
    return v > 0.0f ? v : 0.2f * v;
}

// ---------------------------------------------------------------------------
// edge_index may arrive as int32 or int64 (reference dtype).
// ---------------------------------------------------------------------------
__device__ __forceinline__ void load_edge(const void* eidx, int is32, int e,
                                          int& s, int& d) {
    if (is32) {
        const int2 v = ((const int2*)eidx)[e];
        s = v.x; d = v.y;
    } else {
        const longlong2 v = ((const longlong2*)eidx)[e];
        s = (int)v.x; d = (int)v.y;
    }
}

// ---------------------------------------------------------------------------
// k_cvt: canonicalize edges to int32 SoA (coalesced, no atomics).
// dtype self-detect per block: odd int-words of an int64 buffer are hi-words
// (all 0, ids < 2^31); for int32 they are node ids (nonzero w.h.p.; 64
// samples -> P(miss) ~ (1/50000)^64).
// ---------------------------------------------------------------------------
__global__ __launch_bounds__(256) void k_cvt(
        const void* __restrict__ eidx,
        int* __restrict__ s32, int* __restrict__ d32) {
    __shared__ int s_is32;
    const int t = threadIdx.x;
    if (t < 64) {
        // max index 2*63*25000+1 = 3150001 < 3.2M ints (int32 buffer size)
        int hi = ((const int*)eidx)[2 * (t * 25000) + 1];
        unsigned long long b = __ballot(hi != 0);
        if (t == 0) s_is32 = (b != 0ULL) ? 1 : 0;
    }
    __syncthreads();
    const int is32 = s_is32;
    const int e = blockIdx.x * 256 + t;
    if (e >= N_EDGES) return;
    int s, d;
    load_edge(eidx, is32, e, s, d);
    s32[e] = s;
    d32[e] = d;
}

// ---------------------------------------------------------------------------
// MFMA GEMM: [64 nodes] x [144 cols] per block, K=128, bf16 inputs.
//   cols   0..127 : Wh  (bf16 out)
//   cols 128..135 : s = x . U where U[k][c] = sum_o W[h][k][o]*a[h][o]
//                   (c<4: a_src head c ; c>=4: a_dst head c-4)  -> f32 out
// ---------------------------------------------------------------------------
__global__ __launch_bounds__(256) void k_wh(
        const float* __restrict__ x, const float* __restrict__ weight,
        const float* __restrict__ attn,
        __hip_bfloat16* __restrict__ Wh16, float* __restrict__ sb16) {
    __shared__ float ubuf[128 * 8];            // 4 KB
    __shared__ short xsw[4 * 4 * 64 * 8];      // 16 KB  [wg][kc][lane][j]
    __shared__ short bsw[4 * 9 * 64 * 8];      // 36 KB  [kc][cg][lane][j]
    const int t  = threadIdx.x;
    const int nb = blockIdx.x * 64;

    // ---- U[k][c], c in [0,8)
    {
        int c = t & 7, k0 = t >> 3;            // k0 in [0,32)
        int h = c & 3;
        const float* ap = attn + h * 64 + (c >> 2) * 32;
        for (int k = k0; k < 128; k += 32) {
            const float* wp = weight + h * (IN_DIM * OUT_DIM) + k * OUT_DIM;
            float u = 0.f;
#pragma unroll
            for (int o = 0; o < 32; o += 4) {
                float4 wv = *(const float4*)(wp + o);
                float4 av = *(const float4*)(ap + o);
                u += wv.x * av.x + wv.y * av.y + wv.z * av.z + wv.w * av.w;
            }
            ubuf[k * 8 + c] = u;
        }
    }
    __syncthreads();

    // ---- stage B: weight cols 0..127
    for (int f = t; f < 128 * 128; f += 256) {
        int k = f >> 7, c = f & 127;
        float w = weight[(c >> 5) * (IN_DIM * OUT_DIM) + k * OUT_DIM + (c & 31)];
        int kc = k >> 5, quad = (k >> 3) & 3, j = k & 7;
        bsw[((kc * 9 + (c >> 4)) * 64 + quad * 16 + (c & 15)) * 8 + j] = f2bf(w);
    }
    // ---- stage B: extension cols 128..143 (U, zero-padded)
    for (int f = t; f < 128 * 16; f += 256) {
        int k = f >> 4, c = f & 15;
        float w = (c < 8) ? ubuf[k * 8 + c] : 0.f;
        int kc = k >> 5, quad = (k >> 3) & 3, j = k & 7;
        bsw[((kc * 9 + 8) * 64 + quad * 16 + c) * 8 + j] = f2bf(w);
    }
    // ---- stage A: 64 node rows of x, f32 -> bf16, swizzled
    for (int f = t; f < 64 * 32; f += 256) {
        int n = f >> 5, k = (f & 31) * 4;
        int ng = nb + n; if (ng > N_NODES - 1) ng = N_NODES - 1;
        float4 v = *(const float4*)(x + (size_t)ng * IN_DIM + k);
        int wg = n >> 4, m = n & 15, kc = k >> 5, quad = (k >> 3) & 3, j = k & 7;
        short4 sv = make_short4(f2bf(v.x), f2bf(v.y), f2bf(v.z), f2bf(v.w));
        *(short4*)&xsw[(((wg * 4 + kc) * 64) + quad * 16 + m) * 8 + j] = sv;
    }
    __syncthreads();

    // ---- compute: per wave, 16 nodes x 144 cols, 36 MFMAs
    const int wg = t >> 6, lane = t & 63;
    floatx4 acc[9];
#pragma unroll
    for (int i = 0; i < 9; ++i) acc[i] = (floatx4){0.f, 0.f, 0.f, 0.f};
#pragma unroll
    for (int kc = 0; kc < 4; ++kc) {
        short8 a = *(short8*)&xsw[((wg * 4 + kc) * 64 + lane) * 8];
#pragma unroll
        for (int cg = 0; cg < 9; ++cg) {
            short8 b = *(short8*)&bsw[((kc * 9 + cg) * 64 + lane) * 8];
            acc[cg] = __builtin_amdgcn_mfma_f32_16x16x32_bf16(a, b, acc[cg],
                                                              0, 0, 0);
        }
    }

    // ---- epilogue
    const int col = lane & 15, quad = lane >> 4;
#pragma unroll
    for (int r = 0; r < 4; ++r) {
        int n = nb + wg * 16 + quad * 4 + r;
        if (n >= N_NODES) continue;
#pragma unroll
        for (int cg = 0; cg < 8; ++cg)
            Wh16[(size_t)n * WH_DIM + cg * 16 + col] =
                __float2bfloat16(acc[cg][r]);
        if (col < 8) sb16[(size_t)n * 16 + col] = acc[8][r];
    }
}

// ---------------------------------------------------------------------------
// k_hist: (chunk, window) blocks; LDS histogram, coalesced flush, no atomics.
// ---------------------------------------------------------------------------
__global__ __launch_bounds__(1024) void k_hist(
        const int* __restrict__ d32, int* __restrict__ hist) {
    __shared__ int hbin[WIN];                  // 50 KB
    const int c = blockIdx.x, w = blockIdx.y;
    for (int i = threadIdx.x; i < WIN; i += 1024) hbin[i] = 0;
    __syncthreads();
    const int w0 = w * WIN;
    for (int e = c * CE + threadIdx.x; e < (c + 1) * CE; e += 1024) {
        unsigned u = (unsigned)(d32[e] - w0);
        if (u < WIN) atomicAdd(&hbin[u], 1);
    }
    __syncthreads();
    for (int i = threadIdx.x; i < WIN; i += 1024)
        hist[c * N_NODES + w0 + i] = hbin[i];
}

// ---------------------------------------------------------------------------
// scan: per-dst total over chunks + hierarchical exclusive scan
// off[n] = pre[n] + bbase[n>>8]
// ---------------------------------------------------------------------------
__global__ __launch_bounds__(256) void k_scan1(
        const int* __restrict__ hist, int* __restrict__ pre,
        int* __restrict__ bsum) {
    __shared__ int sh[256];
    const int t = threadIdx.x;
    const int i = blockIdx.x * 256 + t;
    int v = 0;
    if (i < N_NODES)
        for (int c = 0; c < NCHUNK; ++c) v += hist[c * N_NODES + i];
    sh[t] = v;
    __syncthreads();
    for (int d = 1; d < 256; d <<= 1) {
        int u = (t >= d) ? sh[t - d] : 0;
        __syncthreads();
        sh[t] += u;
        __syncthreads();
    }
    if (i < N_NODES) pre[i] = sh[t] - v;
    if (t == 255) bsum[blockIdx.x] = sh[255];
}

__global__ __launch_bounds__(256) void k_scan2(
        const int* __restrict__ bsum, int* __restrict__ bbase) {
    __shared__ int sh[256];
    const int t = threadIdx.x;
    int v = (t < NB_SCAN) ? bsum[t] : 0;
    sh[t] = v;
    __syncthreads();
    for (int d = 1; d < 256; d <<= 1) {
        int u = (t >= d) ? sh[t - d] : 0;
        __syncthreads();
        sh[t] += u;
        __syncthreads();
    }
    if (t < NB_SCAN) bbase[t] = sh[t] - v;
}

// ---------------------------------------------------------------------------
// k_base: in place, hist[c][d] := off[d] + sum_{c'<c} hist[c'][d]
// ---------------------------------------------------------------------------
__global__ __launch_bounds__(256) void k_base(
        const int* __restrict__ pre, const int* __restrict__ bbase,
        int* __restrict__ hist) {
    int d = blockIdx.x * 256 + threadIdx.x;
    if (d >= N_NODES) return;
    int run = pre[d] + bbase[d >> 8];
    for (int c = 0; c < NCHUNK; ++c) {
        int t0 = hist[c * N_NODES + d];
        hist[c * N_NODES + d] = run;
        run += t0;
    }
}

// ---------------------------------------------------------------------------
// k_scatter: (chunk, window) blocks; positions via LDS atomics on bases.
// Window csr region ~1.6 MB stays L2-resident.
// ---------------------------------------------------------------------------
__global__ __launch_bounds__(1024) void k_scatter(
        const int* __restrict__ s32, const int* __restrict__ d32,
        const int* __restrict__ hist, int* __restrict__ csr) {
    __shared__ int pos[WIN];                   // 50 KB
    const int c = blockIdx.x, w = blockIdx.y;
    const int w0 = w * WIN;
    for (int i = threadIdx.x; i < WIN; i += 1024)
        pos[i] = hist[c * N_NODES + w0 + i];
    __syncthreads();
    for (int e = c * CE + threadIdx.x; e < (c + 1) * CE; e += 1024) {
        unsigned u = (unsigned)(d32[e] - w0);
        if (u < WIN) {
            int p = atomicAdd(&pos[u], 1);
            csr[p] = s32[e];
        }
    }
}

// ---------------------------------------------------------------------------
// One wave per dst node. No max pass (softmax shift-invariant; |e| small).
// sb16 row: [0..3]=s_src, [4..7]=s_dst, [8..11]=inv (written here), 64 B.
// Phase D lane map: esl = t>>4 picks 1 of 4 edges, dsl = t&15 picks an
// 8-dim slice -> one dwordx4 covers 4 edges per wave-instruction.
// R3: 16-edge unroll -> 4 independent gathers in flight per wave (MLP 1->4);
// tail groups use pad row sbuf[wv][0] (L1-hot, finite) with a=0.
// inv applied once after the cross-esl shuffle reduce (sum is inv-linear).
// ---------------------------------------------------------------------------
__global__ __launch_bounds__(256) void k_node(
        const int* __restrict__ pre, const int* __restrict__ bbase,
        const int* __restrict__ csr, float* __restrict__ sb16,
        const __hip_bfloat16* __restrict__ Wh16,
        float* __restrict__ out_h) {
    __shared__ int    sbuf[4][CAP];
    __shared__ float4 e4b[4][CAP];                      // exp(e) values
    const int wv = threadIdx.x >> 6;
    const int t  = threadIdx.x & 63;
    const int n  = blockIdx.x * 4 + wv;
    const int beg = pre[n] + bbase[n >> 8];
    const int end = (n + 1 < N_NODES) ? pre[n + 1] + bbase[(n + 1) >> 8]
                                      : N_EDGES;
    const int deg = end - beg;

    const float4 sd = *(const float4*)(sb16 + (size_t)n * 16 + 4);

    // Phase A: ex = exp(lrelu(s_src[src] + s_dst[n])); cache; running sum
    float4 sum = {0.f, 0.f, 0.f, 0.f};
    for (int l = t; l < deg; l += 64) {
        int s = csr[beg + l];
        float4 ss = *(const float4*)(sb16 + (size_t)s * 16);
        float4 ex;
        ex.x = __expf(lrelu(ss.x + sd.x));
        ex.y = __expf(lrelu(ss.y + sd.y));
        ex.z = __expf(lrelu(ss.z + sd.z));
        ex.w = __expf(lrelu(ss.w + sd.w));
        if (l < CAP) { sbuf[wv][l] = s; e4b[wv][l] = ex; }
        sum.x += ex.x; sum.y += ex.y; sum.z += ex.z; sum.w += ex.w;
    }
#pragma unroll
    for (int o = 32; o; o >>= 1) {
        sum.x += __shfl_xor(sum.x, o);
        sum.y += __shfl_xor(sum.y, o);
        sum.z += __shfl_xor(sum.z, o);
        sum.w += __shfl_xor(sum.w, o);
    }
    float4 inv;
    inv.x = 1.0f / (sum.x + 1e-9f); inv.y = 1.0f / (sum.y + 1e-9f);
    inv.z = 1.0f / (sum.z + 1e-9f); inv.w = 1.0f / (sum.w + 1e-9f);
    if (t == 0) *(float4*)(sb16 + (size_t)n * 16 + 8) = inv;

    // Phase D: out[n, dsl*8 .. dsl*8+7] = inv[h] * sum_j ex_j[h]*Wh16[s_j]
    const int esl = t >> 4;            // edge slot within 4-edge group
    const int dsl = t & 15;            // 8-dim slice: dims [dsl*8, dsl*8+8)
    const int h   = dsl >> 2;          // head of this slice (8 | 32)
    const float invh = (h == 0) ? inv.x : (h == 1) ? inv.y
                     : (h == 2) ? inv.z : inv.w;
    const float sdh  = (h == 0) ? sd.x : (h == 1) ? sd.y
                     : (h == 2) ? sd.z : sd.w;
    float acc0 = 0.f, acc1 = 0.f, acc2 = 0.f, acc3 = 0.f;
    float acc4 = 0.f, acc5 = 0.f, acc6 = 0.f, acc7 = 0.f;
    if (deg <= CAP) {
        const int sPad = sbuf[wv][0];
        for (int jb = 0; jb < deg; jb += 16) {
            // gather 4 groups' (s, a) from LDS, then issue 4 independent
            // 16B global loads before any FMA (4 gathers in flight).
            int   sg[4];
            float ag[4];
#pragma unroll
            for (int g = 0; g < 4; ++g) {
                const int idx = jb + g * 4 + esl;
                sg[g] = sPad;
                ag[g] = 0.f;
                if (idx < deg) {
                    sg[g] = sbuf[wv][idx];
                    ag[g] = ((const float*)&e4b[wv][idx])[h];
                }
            }
            uint4 w0 = *(const uint4*)(Wh16 + (size_t)sg[0] * WH_DIM + dsl * 8);
            uint4 w1 = *(const uint4*)(Wh16 + (size_t)sg[1] * WH_DIM + dsl * 8);
            uint4 w2 = *(const uint4*)(Wh16 + (size_t)sg[2] * WH_DIM + dsl * 8);
            uint4 w3 = *(const uint4*)(Wh16 + (size_t)sg[3] * WH_DIM + dsl * 8);
#define ACC8(W, A)                                                            \
            acc0 += (A) * __uint_as_float((W).x << 16);                       \
            acc1 += (A) * __uint_as_float((W).x & 0xffff0000u);               \
            acc2 += (A) * __uint_as_float((W).y << 16);                       \
            acc3 += (A) * __uint_as_float((W).y & 0xffff0000u);               \
            acc4 += (A) * __uint_as_float((W).z << 16);                       \
            acc5 += (A) * __uint_as_float((W).z & 0xffff0000u);               \
            acc6 += (A) * __uint_as_float((W).w << 16);                       \
            acc7 += (A) * __uint_as_float((W).w & 0xffff0000u)
            ACC8(w0, ag[0]);
            ACC8(w1, ag[1]);
            ACC8(w2, ag[2]);
            ACC8(w3, ag[3]);
#undef ACC8
        }
    } else {
        for (int jb = 0; jb < deg; jb += 4) {
            const int idx = jb + esl;
            float a = 0.f;
            int s = sbuf[wv][0];
            if (idx < deg) {
                if (idx < CAP) {
                    s = sbuf[wv][idx];
                    a = ((const float*)&e4b[wv][idx])[h];
                } else {
                    s = csr[beg + idx];
                    a = __expf(lrelu(sb16[(size_t)s * 16 + h] + sdh));
                }
            }
            const uint4 w = *(const uint4*)(Wh16 + (size_t)s * WH_DIM + dsl * 8);
            acc0 += a * __uint_as_float(w.x << 16);
            acc1 += a * __uint_as_float(w.x & 0xffff0000u);
            acc2 += a * __uint_as_float(w.y << 16);
            acc3 += a * __uint_as_float(w.y & 0xffff0000u);
            acc4 += a * __uint_as_float(w.z << 16);
            acc5 += a * __uint_as_float(w.z & 0xffff0000u);
            acc6 += a * __uint_as_float(w.w << 16);
            acc7 += a * __uint_as_float(w.w & 0xffff0000u);
        }
    }
    // reduce across the 4 edge slots (lanes dsl, dsl+16, dsl+32, dsl+48)
    acc0 += __shfl_xor(acc0, 16); acc0 += __shfl_xor(acc0, 32);
    acc1 += __shfl_xor(acc1, 16); acc1 += __shfl_xor(acc1, 32);
    acc2 += __shfl_xor(acc2, 16); acc2 += __shfl_xor(acc2, 32);
    acc3 += __shfl_xor(acc3, 16); acc3 += __shfl_xor(acc3, 32);
    acc4 += __shfl_xor(acc4, 16); acc4 += __shfl_xor(acc4, 32);
    acc5 += __shfl_xor(acc5, 16); acc5 += __shfl_xor(acc5, 32);
    acc6 += __shfl_xor(acc6, 16); acc6 += __shfl_xor(acc6, 32);
    acc7 += __shfl_xor(acc7, 16); acc7 += __shfl_xor(acc7, 32);
    if (t < 16) {
        float* op = out_h + (size_t)n * WH_DIM + dsl * 8;
        float4 o0 = {acc0 * invh, acc1 * invh, acc2 * invh, acc3 * invh};
        float4 o1 = {acc4 * invh, acc5 * invh, acc6 * invh, acc7 * invh};
        *(float4*)op = o0;
        *(float4*)(op + 4) = o1;
    }
}

// ---------------------------------------------------------------------------
// Edge-parallel alpha: coalesced edge reads; dst-side gather (sd+inv) hits
// one 64 B line per edge; coalesced float4 write.
// ---------------------------------------------------------------------------
__global__ __launch_bounds__(256) void k_alpha(
        const int* __restrict__ s32, const int* __restrict__ d32,
        const float* __restrict__ sb16, float* __restrict__ ebuf) {
    int e = blockIdx.x * 256 + threadIdx.x;
    if (e >= N_EDGES) return;
    int s = s32[e], d = d32[e];
    float4 ss = *(const float4*)(sb16 + (size_t)s * 16);
    float4 sd = *(const float4*)(sb16 + (size_t)d * 16 + 4);
    float4 iv = *(const float4*)(sb16 + (size_t)d * 16 + 8);
    float4 a;
    a.x = __expf(lrelu(ss.x + sd.x)) * iv.x;
    a.y = __expf(lrelu(ss.y + sd.y)) * iv.y;
    a.z = __expf(lrelu(ss.z + sd.z)) * iv.z;
    a.w = __expf(lrelu(ss.w + sd.w)) * iv.w;
    *(float4*)(ebuf + (size_t)e * 4) = a;
}

// ---------------------------------------------------------------------------
extern "C" void kernel_launch(void* const* d_in, const int* in_sizes, int n_in,
                              void* d_out, int out_size, void* d_ws, size_t ws_size,
                              hipStream_t stream) {
    const float* x      = (const float*)d_in[0];
    const void*  eidx   = d_in[1];
    const float* weight = (const float*)d_in[2];
    const float* attn   = (const float*)d_in[3];

    float* out   = (float*)d_out;
    float* out_h = out;                                   // [N_NODES, 128]
    float* ebuf  = out + (size_t)N_NODES * WH_DIM;        // [N_EDGES, 4] alpha

    // workspace layout (64-B aligned); total ~41.8 MB (R0-proven)
    char* ws = (char*)d_ws;
    int*   bsum  = (int*)(ws + 64);                       // 784 B
    int*   bbase = (int*)(ws + 896);                      // 784 B
    int*   pre   = (int*)(ws + 2048);                     // 200000 B
    int*   s32   = (int*)(ws + 202112);                   // 6.4 MB
    int*   d32   = (int*)(ws + 6602112);                  // 6.4 MB
    int*   hist  = (int*)(ws + 13002112);                 // 6.4 MB [c][d]
    int*   csr   = (int*)(ws + 19402112);                 // 6.4 MB
    __hip_bfloat16* Wh16 = (__hip_bfloat16*)(ws + 25802112);  // 12.8 MB
    float* sb16  = (float*)(ws + 38602112);               // 3.2 MB [n][16]

    k_cvt<<<(N_EDGES + 255) / 256, 256, 0, stream>>>(eidx, s32, d32);
    k_wh<<<(N_NODES + 63) / 64, 256, 0, stream>>>(x, weight, attn, Wh16, sb16);
    dim3 hg(NCHUNK, NPASS);
    k_hist<<<hg, 1024, 0, stream>>>(d32, hist);
    k_scan1<<<NB_SCAN, 256, 0, stream>>>(hist, pre, bsum);
    k_scan2<<<1, 256, 0, stream>>>(bsum, bbase);
    k_base<<<NB_SCAN, 256, 0, stream>>>(pre, bbase, hist);
    k_scatter<<<hg, 1024, 0, stream>>>(s32, d32, hist, csr);
    k_node<<<N_NODES / 4, 256, 0, stream>>>(pre, bbase, csr, sb16,
                                            Wh16, out_h);
    k_alpha<<<(N_EDGES + 255) / 256, 256, 0, stream>>>(s32, d32, sb16, ebuf);
}